// Round 2
// baseline (52.734 us; speedup 1.0000x reference)
//
#include <hip/hip_runtime.h>

// Pairwise Manhattan (L1) distance.
//   A: [N=1024, D=128] f32, B: [M=4096, D=128] f32 -> out: [N, M] f32
// VALU-bound: 1.07e9 fp32 lane-ops -> 13.7us floor at 78.6e12 ops/s.
//
// Round 2: 128x128 block tile, 8x8 register tile per thread (256 threads).
//  - LDS per FLOP halved vs 4x4: 256*(8+8)/(8*8) = 64 B/cyc/CU needed,
//    under the 85 B/cyc achievable ds_read_b128 ceiling (m134).
//  - Fragments split as two float4 64 apart (tx*4 and 64+tx*4) so LDS reads
//    stay <=2-way bank aliased (free, m136) and C-stores stay float4-coalesced.
//  - Transposed LDS [d][row]; staging lanes span rows -> contiguous
//    conflict-free scalar writes (Round 1 measured 0 conflicts with this).
//  - grid = 256 blocks = 1 block/CU; latency hidden by ILP in unrolled d-loop.

#define D_DIM 128
#define TN 128
#define TM 128
#define DK 64

__global__ __launch_bounds__(256, 1) void manhattan_l1_kernel(
    const float* __restrict__ A, const float* __restrict__ B,
    float* __restrict__ out, int N, int M)
{
    __shared__ float lds_a[DK][TN];  // [d][row]  32 KB
    __shared__ float lds_b[DK][TM];  // [d][col]  32 KB

    const int tid = threadIdx.x;
    const int tx = tid & 15;   // col-group 0..15
    const int ty = tid >> 4;   // row-group 0..15

    const int row0 = blockIdx.y * TN;
    const int col0 = blockIdx.x * TM;

    // Staging mapping: 256 threads cover 128 rows x 2 d-groups.
    const int sr = tid & 127;       // row (A) / col (B)
    const int sg = (tid >> 7) * 4;  // d4 base within 8-float stripe: 0 or 4

    float acc[2][2][4][4] = {};  // [row-half][col-half][i][j]

    for (int dk = 0; dk < D_DIM; dk += DK) {
        __syncthreads();  // protect LDS from previous chunk's readers
        // Stage transposed: lds[d][row]. Lanes span contiguous rows ->
        // conflict-free scalar LDS writes.
        #pragma unroll
        for (int j = 0; j < 8; ++j) {
            const int d4 = sg + j * 8;
            const float4 va = *reinterpret_cast<const float4*>(
                &A[(size_t)(row0 + sr) * D_DIM + dk + d4]);
            lds_a[d4 + 0][sr] = va.x;
            lds_a[d4 + 1][sr] = va.y;
            lds_a[d4 + 2][sr] = va.z;
            lds_a[d4 + 3][sr] = va.w;
            const float4 vb = *reinterpret_cast<const float4*>(
                &B[(size_t)(col0 + sr) * D_DIM + dk + d4]);
            lds_b[d4 + 0][sr] = vb.x;
            lds_b[d4 + 1][sr] = vb.y;
            lds_b[d4 + 2][sr] = vb.z;
            lds_b[d4 + 3][sr] = vb.w;
        }
        __syncthreads();

        // Compute: per d-step, 4x ds_read_b128 + 128 |a-b| accumulates.
        #pragma unroll 8
        for (int d = 0; d < DK; ++d) {
            float av[2][4], bv[2][4];
            *reinterpret_cast<float4*>(av[0]) =
                *reinterpret_cast<const float4*>(&lds_a[d][ty * 4]);
            *reinterpret_cast<float4*>(av[1]) =
                *reinterpret_cast<const float4*>(&lds_a[d][64 + ty * 4]);
            *reinterpret_cast<float4*>(bv[0]) =
                *reinterpret_cast<const float4*>(&lds_b[d][tx * 4]);
            *reinterpret_cast<float4*>(bv[1]) =
                *reinterpret_cast<const float4*>(&lds_b[d][64 + tx * 4]);
            #pragma unroll
            for (int ri = 0; ri < 2; ++ri)
                #pragma unroll
                for (int ci = 0; ci < 2; ++ci)
                    #pragma unroll
                    for (int i = 0; i < 4; ++i)
                        #pragma unroll
                        for (int j = 0; j < 4; ++j)
                            acc[ri][ci][i][j] +=
                                __builtin_fabsf(av[ri][i] - bv[ci][j]);
        }
    }

    // Epilogue: coalesced float4 stores.
    #pragma unroll
    for (int ri = 0; ri < 2; ++ri) {
        #pragma unroll
        for (int i = 0; i < 4; ++i) {
            const size_t row = (size_t)(row0 + ri * 64 + ty * 4 + i);
            float4 v0, v1;
            v0.x = acc[ri][0][i][0]; v0.y = acc[ri][0][i][1];
            v0.z = acc[ri][0][i][2]; v0.w = acc[ri][0][i][3];
            v1.x = acc[ri][1][i][0]; v1.y = acc[ri][1][i][1];
            v1.z = acc[ri][1][i][2]; v1.w = acc[ri][1][i][3];
            *reinterpret_cast<float4*>(&out[row * M + col0 + tx * 4]) = v0;
            *reinterpret_cast<float4*>(&out[row * M + col0 + 64 + tx * 4]) = v1;
        }
    }
}

extern "C" void kernel_launch(void* const* d_in, const int* in_sizes, int n_in,
                              void* d_out, int out_size, void* d_ws, size_t ws_size,
                              hipStream_t stream) {
    const float* A = (const float*)d_in[0];
    const float* B = (const float*)d_in[1];
    float* out = (float*)d_out;

    const int N = in_sizes[0] / D_DIM;  // 1024
    const int M = in_sizes[1] / D_DIM;  // 4096

    dim3 grid(M / TM, N / TN);  // (32, 8) = 256 blocks = 1/CU
    dim3 block(256);
    manhattan_l1_kernel<<<grid, block, 0, stream>>>(A, B, out, N, M);
}

// Round 3
// 47.284 us; speedup vs baseline: 1.1153x; 1.1153x over previous
//
#include <hip/hip_runtime.h>

// Pairwise Manhattan (L1) distance.
//   A: [N=1024, D=128] f32, B: [M=4096, D=128] f32 -> out: [N, M] f32
// VALU floor: 1.07e9 fp32 lane-ops -> 13.7us at 78.6e12 ops/s.
//
// Round 3: fix Round 2's occupancy collapse (1 wave/SIMD) while keeping a
// good LDS-instr ratio.
//  - 64x128 block tile, 256 threads, 4 rows x 8 cols per thread (32 outputs)
//    -> 131072 threads = 2048 waves = 8 waves/CU = 2 waves/SIMD (TLP back).
//  - LDS-demand ratio 3(r+c)/(rc) = 1.125 -> ~15.5us LDS floor (vs 1.5 @4x4).
//  - 48 KB LDS -> 2 blocks/CU resident; grid = 512 = 2 blocks/CU exactly.
//  - T14-style early issue: chunk-1 global loads issued before chunk-0
//    compute; vmcnt wait lands after 64 d-steps of VALU work.
//  - Proven patterns: transposed [d][row] LDS, contiguous scalar staging
//    writes (0 conflicts measured), <=2-way-aliased b128 fragment reads.

#define D_DIM 128
#define TN 64
#define TM 128
#define DK 64

__global__ __launch_bounds__(256, 2) void manhattan_l1_kernel(
    const float* __restrict__ A, const float* __restrict__ B,
    float* __restrict__ out, int M)
{
    __shared__ float lds_a[DK][TN];   // [d][row] 16 KB
    __shared__ float lds_b[DK][TM];   // [d][col] 32 KB

    const int tid = threadIdx.x;
    const int tx = tid & 15;   // col-group
    const int ty = tid >> 4;   // row-group 0..15

    const int row0 = blockIdx.y * TN;
    const int col0 = blockIdx.x * TM;

    // Staging mapping
    const int ar = tid & 63;        // A row
    const int af4 = tid >> 6;       // 0..3
    const int bc = tid & 127;       // B col
    const int bf4 = tid >> 7;       // 0..1

    const float* Abase = A + (size_t)(row0 + ar) * D_DIM;
    const float* Bbase = B + (size_t)(col0 + bc) * D_DIM;

    float4 pa[4], pb[8];

    // ---- chunk 0: global -> regs ----
    #pragma unroll
    for (int j = 0; j < 4; ++j)
        pa[j] = *reinterpret_cast<const float4*>(Abase + (af4 * 4 + j) * 4);
    #pragma unroll
    for (int j = 0; j < 8; ++j)
        pb[j] = *reinterpret_cast<const float4*>(Bbase + (bf4 * 8 + j) * 4);

    // ---- chunk 0: regs -> LDS (transposed, contiguous writes) ----
    #pragma unroll
    for (int j = 0; j < 4; ++j) {
        const int d0 = (af4 * 4 + j) * 4;
        lds_a[d0 + 0][ar] = pa[j].x; lds_a[d0 + 1][ar] = pa[j].y;
        lds_a[d0 + 2][ar] = pa[j].z; lds_a[d0 + 3][ar] = pa[j].w;
    }
    #pragma unroll
    for (int j = 0; j < 8; ++j) {
        const int d0 = (bf4 * 8 + j) * 4;
        lds_b[d0 + 0][bc] = pb[j].x; lds_b[d0 + 1][bc] = pb[j].y;
        lds_b[d0 + 2][bc] = pb[j].z; lds_b[d0 + 3][bc] = pb[j].w;
    }
    __syncthreads();

    // ---- issue chunk-1 global loads EARLY (hide under chunk-0 compute) ----
    #pragma unroll
    for (int j = 0; j < 4; ++j)
        pa[j] = *reinterpret_cast<const float4*>(Abase + DK + (af4 * 4 + j) * 4);
    #pragma unroll
    for (int j = 0; j < 8; ++j)
        pb[j] = *reinterpret_cast<const float4*>(Bbase + DK + (bf4 * 8 + j) * 4);

    float acc[2][4][4] = {};  // [col-half][i][j]

#define COMPUTE_CHUNK                                                         \
    _Pragma("unroll 8")                                                       \
    for (int d = 0; d < DK; ++d) {                                            \
        const float4 av  = *reinterpret_cast<const float4*>(&lds_a[d][ty * 4]); \
        const float4 bv0 = *reinterpret_cast<const float4*>(&lds_b[d][tx * 4]); \
        const float4 bv1 = *reinterpret_cast<const float4*>(&lds_b[d][64 + tx * 4]); \
        const float a_[4]  = {av.x, av.y, av.z, av.w};                        \
        const float b0_[4] = {bv0.x, bv0.y, bv0.z, bv0.w};                    \
        const float b1_[4] = {bv1.x, bv1.y, bv1.z, bv1.w};                    \
        _Pragma("unroll")                                                     \
        for (int i = 0; i < 4; ++i) {                                         \
            _Pragma("unroll")                                                 \
            for (int j = 0; j < 4; ++j) {                                     \
                acc[0][i][j] += __builtin_fabsf(a_[i] - b0_[j]);              \
                acc[1][i][j] += __builtin_fabsf(a_[i] - b1_[j]);              \
            }                                                                 \
        }                                                                     \
    }

    COMPUTE_CHUNK;           // chunk 0

    __syncthreads();         // chunk-0 LDS reads done

    // ---- chunk 1: regs -> LDS ----
    #pragma unroll
    for (int j = 0; j < 4; ++j) {
        const int d0 = (af4 * 4 + j) * 4;
        lds_a[d0 + 0][ar] = pa[j].x; lds_a[d0 + 1][ar] = pa[j].y;
        lds_a[d0 + 2][ar] = pa[j].z; lds_a[d0 + 3][ar] = pa[j].w;
    }
    #pragma unroll
    for (int j = 0; j < 8; ++j) {
        const int d0 = (bf4 * 8 + j) * 4;
        lds_b[d0 + 0][bc] = pb[j].x; lds_b[d0 + 1][bc] = pb[j].y;
        lds_b[d0 + 2][bc] = pb[j].z; lds_b[d0 + 3][bc] = pb[j].w;
    }
    __syncthreads();

    COMPUTE_CHUNK;           // chunk 1

    // ---- epilogue: coalesced float4 stores ----
    #pragma unroll
    for (int i = 0; i < 4; ++i) {
        const size_t row = (size_t)(row0 + ty * 4 + i);
        float4 v0, v1;
        v0.x = acc[0][i][0]; v0.y = acc[0][i][1];
        v0.z = acc[0][i][2]; v0.w = acc[0][i][3];
        v1.x = acc[1][i][0]; v1.y = acc[1][i][1];
        v1.z = acc[1][i][2]; v1.w = acc[1][i][3];
        *reinterpret_cast<float4*>(&out[row * M + col0 + tx * 4]) = v0;
        *reinterpret_cast<float4*>(&out[row * M + col0 + 64 + tx * 4]) = v1;
    }
#undef COMPUTE_CHUNK
}

extern "C" void kernel_launch(void* const* d_in, const int* in_sizes, int n_in,
                              void* d_out, int out_size, void* d_ws, size_t ws_size,
                              hipStream_t stream) {
    const float* A = (const float*)d_in[0];
    const float* B = (const float*)d_in[1];
    float* out = (float*)d_out;

    const int N = in_sizes[0] / D_DIM;  // 1024
    const int M = in_sizes[1] / D_DIM;  // 4096

    dim3 grid(M / TM, N / TN);  // (32, 16) = 512 blocks = 2/CU
    dim3 block(256);
    manhattan_l1_kernel<<<grid, block, 0, stream>>>(A, B, out, M);
}